// Round 13
// baseline (111.170 us; speedup 1.0000x reference)
//
#include <hip/hip_runtime.h>
#include <hip/hip_bf16.h>

typedef __attribute__((ext_vector_type(8))) short short8;
typedef __attribute__((ext_vector_type(4))) float float4v;
typedef __attribute__((address_space(3))) unsigned int as3u32;
typedef __attribute__((address_space(1))) unsigned int as1u32;

#define DIN 128
#define SSIZE 1024
#define MLGK 256
#define DOUT 10
#define TM 32   // x-rows per block; 2 waves x 16 rows
#define TS 32   // anchors per staged tile
#define NT 32   // anchor tiles
#define NTHR 128

union pk8 { unsigned int w[4]; short8 s8; };

#if __has_builtin(__builtin_amdgcn_sqrtf)
#define fsqrt_fast __builtin_amdgcn_sqrtf
#else
#define fsqrt_fast sqrtf
#endif

__device__ inline unsigned short f2bf(float f) {  // RNE (pre-kernels)
  unsigned int u = __float_as_uint(f);
  u = (u + 0x7FFFu + ((u >> 16) & 1u)) >> 16;
  return (unsigned short)u;
}
__device__ inline float bf2f(unsigned short h) {
  return __uint_as_float(((unsigned int)h) << 16);
}
// packed RNE f32->bf16 (header path; numerically identical to f2bf)
__device__ inline unsigned int pkbf(float lo, float hi) {
  __hip_bfloat162 p = __float22bfloat162_rn(make_float2(lo, hi));
  unsigned int r;
  __builtin_memcpy(&r, &p, 4);
  return r;
}
__device__ inline float mish_f(float x) {
  if (x > 30.f) return x;
  float e = __expf(x);
  float u = 1.f + e;
  float u2 = u * u;
  return x * (u2 - 1.f) / (u2 + 1.f);
}
// element-index XOR swizzle; identical to the chunk-XOR used by stage8k
__device__ inline int swz(int row, int col) {
  return row * DIN + (col ^ ((row & 7) << 3));
}

// Stage a 32x128 bf16 tile (row stride DIN) into an 8KB LDS region via
// global_load_lds width=16, 128 threads. LDS dest LINEAR in lane order
// (rule #21); XOR swizzle applied by permuting the GLOBAL source chunk.
__device__ inline void stage8k(const unsigned short* __restrict__ gsrc,
                               unsigned short* region, int tid) {
#pragma unroll
  for (int it = 0; it < 4; ++it) {
    int slot = it * NTHR + tid;      // 0..511
    int r = slot >> 4;               // 0..31
    int c8 = (slot & 15) ^ (r & 7);
    __builtin_amdgcn_global_load_lds((const as1u32*)(gsrc + r * DIN + c8 * 8),
                                     (as3u32*)(region + slot * 8), 16, 0, 0);
  }
}

// ---------- wide precompute kernels (fp32, one element per thread) ----------

__global__ __launch_bounds__(256) void k_pre1(
    const float* __restrict__ W1, const float* __restrict__ W2,
    const float* __restrict__ Wc, const float* __restrict__ Wa,
    const float* __restrict__ mlg,
    unsigned short* W1b, unsigned short* W2b, unsigned short* Wcb,
    float* anc_raw) {
  const int blk = blockIdx.x;
  const int tid = threadIdx.x;
  if (blk < 192) {
    int i = blk * 256 + tid;  // 49152 total
    if (i < 16384) {
      W1b[i] = f2bf(W1[i]);
    } else if (i < 32768) {
      W2b[i - 16384] = f2bf(W2[i - 16384]);
    } else {
      int j = i - 32768;  // [16][1024] padded Wc (rows >= DOUT zero)
      int o = j >> 10;
      int s = j & 1023;
      Wcb[j] = (o < DOUT) ? f2bf(Wc[o * SSIZE + s]) : (unsigned short)0;
    }
    return;
  }
  int i = (blk - 192) * 256 + tid;  // 1024*128
  int s = i >> 7, d = i & 127;
  float acc = 0.f;
  for (int k = 0; k < MLGK; ++k) acc = fmaf(Wa[s * MLGK + k], mlg[k * DIN + d], acc);
  anc_raw[i] = tanhf(acc);
}

__global__ __launch_bounds__(256) void k_pre2(const float* __restrict__ anc_raw,
                                              const float* __restrict__ W1,
                                              const float* __restrict__ b1,
                                              float* anc_h) {
  int i = blockIdx.x * 256 + threadIdx.x;  // 1024*128
  int r = i >> 7, d = i & 127;
  float acc = 0.f;
  const float* a = anc_raw + r * DIN;
  const float* w = W1 + d * DIN;
  for (int k = 0; k < DIN; ++k) acc = fmaf(a[k], w[k], acc);
  anc_h[i] = mish_f(acc + b1[d]);
}

__global__ __launch_bounds__(256) void k_pre3(const float* __restrict__ anc_h,
                                              const float* __restrict__ W2,
                                              const float* __restrict__ b2,
                                              unsigned short* ancb, float* a2) {
  __shared__ float part[4];
  const int tid = threadIdx.x;
  const int row = blockIdx.x * 2 + (tid >> 7);
  const int d = tid & 127;
  float acc = 0.f;
  const float* a = anc_h + (size_t)row * DIN;
  const float* w = W2 + d * DIN;
  for (int k = 0; k < DIN; ++k) acc = fmaf(a[k], w[k], acc);
  unsigned short mb = f2bf(mish_f(acc + b2[d]));
  ancb[(size_t)row * DIN + d] = mb;
  float v = bf2f(mb);
  float p = v * v;
  p += __shfl_xor(p, 1);  p += __shfl_xor(p, 2);  p += __shfl_xor(p, 4);
  p += __shfl_xor(p, 8);  p += __shfl_xor(p, 16); p += __shfl_xor(p, 32);
  if ((tid & 63) == 0) part[tid >> 6] = p;
  __syncthreads();
  if (tid == 0)   a2[row]     = part[0] + part[1];
  if (tid == 128) a2[row]     = part[2] + part[3];
}

// ---------- fused main kernel ----------
// R12 geometry/numerics, ONE change: the dist loop's __syncthreads() drains
// (s_waitcnt vmcnt(0) before s_barrier) are replaced by the T3/T4 pattern —
// raw s_barrier + counted "s_waitcnt vmcnt(8)". Per-iteration vm issue is
// UNIFORM (4 a2/Wc + 4 stage, masked indices even in the tail) so vmcnt(8)
// always means: stage(t) landed; stage(t+1) + prefetch(t+1) still in flight.

__global__ __launch_bounds__(NTHR, 8) void k_main(
    const float* __restrict__ x, const float* __restrict__ b1,
    const float* __restrict__ b2, const float* __restrict__ bc,
    const unsigned short* __restrict__ W1b, const unsigned short* __restrict__ W2b,
    const unsigned short* __restrict__ Wcb, const unsigned short* __restrict__ ancb,
    const float* __restrict__ a2, float* __restrict__ out) {
  __shared__ __align__(16) unsigned short reg0[TM * DIN];  // h/x_dml; anchor buf A
  __shared__ __align__(16) unsigned short reg1[TM * DIN];  // W quarters; anchor buf B

  const int tid = threadIdx.x;
  const int lane = tid & 63;
  const int l15 = lane & 15;
  const int lhi = lane >> 4;
  const int n0 = blockIdx.x * TM;
  const int rbase = (tid >> 6) * 16;   // wave 0 -> rows 0-15, wave 1 -> 16-31

  // issue first W quarter stage immediately; x loads fly underneath
  stage8k(W1b, reg1, tid);

  // ---- x rows -> bf16 A-fragments (global -> reg) ----
  short8 af[4];
#pragma unroll
  for (int kk = 0; kk < 4; ++kk) {
    const float* p = x + (size_t)(n0 + rbase + l15) * DIN + kk * 32 + lhi * 8;
    float4 u = *(const float4*)p;
    float4 v = *(const float4*)(p + 4);
    pk8 a;
    a.w[0] = pkbf(u.x, u.y);
    a.w[1] = pkbf(u.z, u.w);
    a.w[2] = pkbf(v.x, v.y);
    a.w[3] = pkbf(v.z, v.w);
    af[kk] = a.s8;
  }

  // ---- encode: 2 layers x 4 staged 32-col quarters of W ----
  short8 ah[4];
#pragma unroll
  for (int kk = 0; kk < 4; ++kk) ah[kk] = af[kk];
#pragma unroll 1
  for (int qq = 0; qq < 8; ++qq) {
    const int layer = qq >> 2;
    const int q = qq & 3;
    const float* bias = layer ? b2 : b1;
    if (q == 0 && layer == 1) {
#pragma unroll
      for (int kk = 0; kk < 4; ++kk)
        ah[kk] = *(const short8*)&reg0[swz(rbase + l15, kk * 32 + lhi * 8)];
    }
    __syncthreads();  // quarter qq staged (vmcnt drained by barrier)
    float4v acc0 = (float4v){0.f, 0.f, 0.f, 0.f};
    float4v acc1 = (float4v){0.f, 0.f, 0.f, 0.f};
#pragma unroll
    for (int kk = 0; kk < 4; ++kk) {
      int k = kk * 32 + lhi * 8;
      short8 bA = *(const short8*)&reg1[swz(l15, k)];
      short8 bB = *(const short8*)&reg1[swz(16 + l15, k)];
      acc0 = __builtin_amdgcn_mfma_f32_16x16x32_bf16(ah[kk], bA, acc0, 0, 0, 0);
      acc1 = __builtin_amdgcn_mfma_f32_16x16x32_bf16(ah[kk], bB, acc1, 0, 0, 0);
    }
    __syncthreads();  // all waves done reading reg1
    if (qq < 7) {
      const unsigned short* Wn = (qq + 1 < 4) ? W1b + (size_t)((qq + 1) * 32) * DIN
                                              : W2b + (size_t)(((qq + 1) & 3) * 32) * DIN;
      stage8k(Wn, reg1, tid);
    }
#pragma unroll
    for (int ct = 0; ct < 2; ++ct) {
      float4v accv = ct ? acc1 : acc0;
      int col = q * 32 + ct * 16 + l15;
      float bv = bias[col];
      float m0 = mish_f(accv[0] + bv);
      float m1 = mish_f(accv[1] + bv);
      float m2 = mish_f(accv[2] + bv);
      float m3 = mish_f(accv[3] + bv);
      unsigned int w01 = pkbf(m0, m1);
      unsigned int w23 = pkbf(m2, m3);
      int r0 = rbase + lhi * 4;
      reg0[swz(r0 + 0, col)] = (unsigned short)(w01 & 0xffff);
      reg0[swz(r0 + 1, col)] = (unsigned short)(w01 >> 16);
      reg0[swz(r0 + 2, col)] = (unsigned short)(w23 & 0xffff);
      reg0[swz(r0 + 3, col)] = (unsigned short)(w23 >> 16);
    }
  }

  // ---- hoist x_dml B-fragments; row norm from the rounded registers ----
  short8 bx[4];
#pragma unroll
  for (int kk = 0; kk < 4; ++kk)
    bx[kk] = *(const short8*)&reg0[swz(rbase + l15, kk * 32 + lhi * 8)];
  float x2v = 0.f;
#pragma unroll
  for (int kk = 0; kk < 4; ++kk)
#pragma unroll
    for (int e = 0; e < 8; ++e) {
      float v = bf2f((unsigned short)bx[kk][e]);
      x2v = fmaf(v, v, x2v);
    }
  x2v += __shfl_xor(x2v, 16);
  x2v += __shfl_xor(x2v, 32);   // full row-norm of row rbase+l15

  // ---- prefetch tile 0's a2 / Wc (named scalars) ----
  const unsigned short* wcrow = Wcb + l15 * SSIZE;
  float4 av0 = *(const float4*)(a2 + lhi * 4);
  float4 av1 = *(const float4*)(a2 + 16 + lhi * 4);
  uint2 wv0 = *(const uint2*)(wcrow + lhi * 4);
  uint2 wv1 = *(const uint2*)(wcrow + 16 + lhi * 4);
  __syncthreads();              // everyone done with reg0 before anchor staging

  // ---- distance + in-register logits: counted-vmcnt pipeline ----
  float4v lacc = (float4v){0.f, 0.f, 0.f, 0.f};

  stage8k(ancb, reg0, tid);  // tile 0 -> buf A
#pragma unroll 1
  for (int t = 0; t < NT; ++t) {
    __builtin_amdgcn_s_barrier();          // all waves done reading the buffer
    __builtin_amdgcn_sched_barrier(0);     // we are about to overwrite (t-1's)
    // issue 4 vm: next tile's a2/Wc prefetch (masked; uniform in tail)
    const int tn = (t + 1) & (NT - 1);
    const float* a2n = a2 + tn * TS + lhi * 4;
    const unsigned short* wcn = wcrow + tn * TS + lhi * 4;
    float4 an0 = *(const float4*)(a2n + 0);
    float4 an1 = *(const float4*)(a2n + 16);
    uint2 wn0 = *(const uint2*)(wcn + 0);
    uint2 wn1 = *(const uint2*)(wcn + 16);
    // issue 4 vm: stage tile t+1 into the other buffer (masked index in tail)
    stage8k(ancb + (size_t)tn * TS * DIN, (t & 1) ? reg0 : reg1, tid);
    __builtin_amdgcn_sched_barrier(0);
    asm volatile("s_waitcnt vmcnt(8)" ::: "memory");  // stage(t) landed; 8 newer in flight
    __builtin_amdgcn_sched_barrier(0);
    __builtin_amdgcn_s_barrier();          // all waves' stage(t) visible
    __builtin_amdgcn_sched_barrier(0);

    const unsigned short* buf = (t & 1) ? reg1 : reg0;
    float4v acc0 = (float4v){0.f, 0.f, 0.f, 0.f};
    float4v acc1 = (float4v){0.f, 0.f, 0.f, 0.f};
    __builtin_amdgcn_s_setprio(1);
#pragma unroll
    for (int kk = 0; kk < 4; ++kk) {
      int k = kk * 32 + lhi * 8;
      short8 aA = *(const short8*)&buf[swz(l15, k)];
      short8 aB = *(const short8*)&buf[swz(16 + l15, k)];
      acc0 = __builtin_amdgcn_mfma_f32_16x16x32_bf16(aA, bx[kk], acc0, 0, 0, 0);
      acc1 = __builtin_amdgcn_mfma_f32_16x16x32_bf16(aB, bx[kk], acc1, 0, 0, 0);
    }
    __builtin_amdgcn_s_setprio(0);
    // epilogue: dist -> bf16; one logits MFMA (ct0 k-slots 0-3, ct1 4-7)
    {
      pk8 A, B;
      float d0 = fsqrt_fast(fmaxf(fmaf(-2.f, acc0[0], x2v + av0.x), 0.f));
      float d1 = fsqrt_fast(fmaxf(fmaf(-2.f, acc0[1], x2v + av0.y), 0.f));
      float d2 = fsqrt_fast(fmaxf(fmaf(-2.f, acc0[2], x2v + av0.z), 0.f));
      float d3 = fsqrt_fast(fmaxf(fmaf(-2.f, acc0[3], x2v + av0.w), 0.f));
      A.w[0] = wv0.x; A.w[1] = wv0.y;
      B.w[0] = pkbf(d0, d1); B.w[1] = pkbf(d2, d3);
      float e0 = fsqrt_fast(fmaxf(fmaf(-2.f, acc1[0], x2v + av1.x), 0.f));
      float e1 = fsqrt_fast(fmaxf(fmaf(-2.f, acc1[1], x2v + av1.y), 0.f));
      float e2 = fsqrt_fast(fmaxf(fmaf(-2.f, acc1[2], x2v + av1.z), 0.f));
      float e3 = fsqrt_fast(fmaxf(fmaf(-2.f, acc1[3], x2v + av1.w), 0.f));
      A.w[2] = wv1.x; A.w[3] = wv1.y;
      B.w[2] = pkbf(e0, e1); B.w[3] = pkbf(e2, e3);
      lacc = __builtin_amdgcn_mfma_f32_16x16x32_bf16(A.s8, B.s8, lacc, 0, 0, 0);
    }
    // rotate prefetched state (named scalars)
    av0 = an0; av1 = an1; wv0 = wn0; wv1 = wn1;
  }
  float4v L = lacc;

  // ---- bias + log_softmax + store (lane holds logits[lhi*4+j][row l15]) ----
  {
    const int xrow = n0 + rbase + l15;
    float v[4];
    float m4 = -1e30f;
#pragma unroll
    for (int j = 0; j < 4; ++j) {
      int o = lhi * 4 + j;
      v[j] = (o < DOUT) ? (L[j] + bc[o]) : -1e30f;
      m4 = fmaxf(m4, v[j]);
    }
    m4 = fmaxf(m4, __shfl_xor(m4, 16));
    m4 = fmaxf(m4, __shfl_xor(m4, 32));
    float es = 0.f;
#pragma unroll
    for (int j = 0; j < 4; ++j) {
      int o = lhi * 4 + j;
      es += (o < DOUT) ? __expf(v[j] - m4) : 0.f;
    }
    es += __shfl_xor(es, 16);
    es += __shfl_xor(es, 32);
    float ls = logf(es);
#pragma unroll
    for (int j = 0; j < 4; ++j) {
      int o = lhi * 4 + j;
      if (o < DOUT) out[(size_t)xrow * DOUT + o] = v[j] - m4 - ls;
    }
  }
}

extern "C" void kernel_launch(void* const* d_in, const int* in_sizes, int n_in,
                              void* d_out, int out_size, void* d_ws, size_t ws_size,
                              hipStream_t stream) {
  const float* x   = (const float*)d_in[0];
  const float* mlg = (const float*)d_in[1];
  const float* W1  = (const float*)d_in[2];
  const float* b1  = (const float*)d_in[3];
  const float* W2  = (const float*)d_in[4];
  const float* b2  = (const float*)d_in[5];
  const float* Wa  = (const float*)d_in[6];
  const float* Wc  = (const float*)d_in[7];
  const float* bc  = (const float*)d_in[8];
  float* out = (float*)d_out;

  // workspace layout (~1.41 MB total)
  unsigned short* W1b  = (unsigned short*)d_ws;        // 16384 bf16
  unsigned short* W2b  = W1b + 16384;                  // 16384 bf16
  unsigned short* Wcb  = W2b + 16384;                  // 16*1024 bf16 (zero-padded)
  unsigned short* ancb = Wcb + 16384;                  // 1024*128 bf16
  float* a2      = (float*)(ancb + SSIZE * DIN);       // 1024 f32
  float* anc_raw = a2 + SSIZE;                         // 1024*128 f32
  float* anc_h   = anc_raw + SSIZE * DIN;              // 1024*128 f32

  k_pre1<<<704, 256, 0, stream>>>(W1, W2, Wc, Wa, mlg, W1b, W2b, Wcb, anc_raw);
  k_pre2<<<512, 256, 0, stream>>>(anc_raw, W1, b1, anc_h);
  k_pre3<<<512, 256, 0, stream>>>(anc_h, W2, b2, ancb, a2);
  k_main<<<2048, NTHR, 0, stream>>>(x, b1, b2, bc, W1b, W2b, Wcb, ancb, a2, out);
}